// Round 11
// baseline (360.956 us; speedup 1.0000x reference)
//
#include <hip/hip_runtime.h>
#include <math.h>

#define NEGINF (-INFINITY)
#define AGENT __HIP_MEMORY_SCOPE_AGENT
#define WG    __HIP_MEMORY_SCOPE_WORKGROUP

typedef float fvec4 __attribute__((ext_vector_type(4)));

template <int M>
__device__ __forceinline__ float qbcast(float v) {
    // DPP quad_perm broadcast of lane M within each 4-lane quad (VALU, no LDS)
    return __int_as_float(
        __builtin_amdgcn_update_dpp(0, __float_as_int(v), M * 0x55, 0xF, 0xF, true));
}
__device__ __forceinline__ float fsigmoid(float z) { return 1.f / (1.f + __expf(-z)); }
__device__ __forceinline__ float ftanh(float z) {
    z = fminf(fmaxf(z, -20.f), 20.f);
    float e = __expf(2.f * z);
    return (e - 1.f) / (e + 1.f);
}
__device__ __forceinline__ float dot8(const float4& a, const float4& b,
                                      const float* __restrict__ w) {
    return a.x * w[0] + a.y * w[1] + a.z * w[2] + a.w * w[3] +
           b.x * w[4] + b.y * w[5] + b.z * w[6] + b.w * w[7];
}

// One fused kernel, 2049 blocks x 448 threads.
// Block 0 = consumer: wave 0 runs the LSTM chain from an LDS xd-ring;
//   waves 1..6 are copy/xd engines (acquire cnt[s], load emb/femb, compute
//   gate x-dots, deposit in ring, release ready[s]).
// Blocks 1..2048 = producers: EXACT round-9 stream (linear image sweep, NT,
//   448 full-active lanes) + inline prep tail; publish emb/femb + release cnt.
__global__ __launch_bounds__(448, 7) void fused_kernel(
    const float* __restrict__ frames, const float* __restrict__ Wf,
    const float* __restrict__ bf, const float* __restrict__ We,
    const float* __restrict__ be, const float* __restrict__ Wih,
    const float* __restrict__ Whh, const float* __restrict__ bih,
    const float* __restrict__ bhh, const float* __restrict__ Wp,
    const float* __restrict__ bp, float* __restrict__ out_pooled,
    float* __restrict__ out_fc, float* __restrict__ prog,
    float* __restrict__ fprog, int* __restrict__ cnt,
    float* __restrict__ emb, float* __restrict__ femb) {
    extern __shared__ float ring[];      // [16 slots][8][64] floats = 32 KB
    __shared__ int ready[128];
    __shared__ int consumed;
    int tid = threadIdx.x;

    if (blockIdx.x == 0) {
        // ---------------- consumer ----------------
        for (int i = tid; i < 128; i += 448) ready[i] = 0;
        if (tid == 0) consumed = 0;
        __syncthreads();
        int w = tid >> 6;

        if (w == 0) {
            // ---- chain wave: 16 batches x 4 hidden lanes ----
            int b = tid >> 2, k = tid & 3;
            float whh_r[4][4], wpv[4];
#pragma unroll
            for (int g = 0; g < 4; g++) {
                int row = g * 4 + k;
#pragma unroll
                for (int m = 0; m < 4; m++) whh_r[g][m] = Whh[row * 4 + m];
            }
#pragma unroll
            for (int m = 0; m < 4; m++) wpv[m] = Wp[m];
            float bpv = bp[0];

            while (!__hip_atomic_load(&ready[0], __ATOMIC_ACQUIRE, WG))
                __builtin_amdgcn_s_sleep(1);
            float cur[8];
#pragma unroll
            for (int i = 0; i < 8; ++i) cur[i] = ring[i * 64 + tid];

            float h0 = 0.f, h1r = 0.f, h2r = 0.f, h3r = 0.f, ck = 0.f;
            for (int s = 0; s < 128; ++s) {
                // ---- cell 1 (xd precomputed by copy waves) ----
                float g0 = cur[0] + h0 * whh_r[0][0] + h1r * whh_r[0][1] + h2r * whh_r[0][2] + h3r * whh_r[0][3];
                float g1 = cur[1] + h0 * whh_r[1][0] + h1r * whh_r[1][1] + h2r * whh_r[1][2] + h3r * whh_r[1][3];
                float g2 = cur[2] + h0 * whh_r[2][0] + h1r * whh_r[2][1] + h2r * whh_r[2][2] + h3r * whh_r[2][3];
                float g3 = cur[3] + h0 * whh_r[3][0] + h1r * whh_r[3][1] + h2r * whh_r[3][2] + h3r * whh_r[3][3];
                float c1  = fsigmoid(g1) * ck + fsigmoid(g0) * ftanh(g2);
                float hk1 = fsigmoid(g3) * ftanh(c1);
                float b0 = qbcast<0>(hk1), b1 = qbcast<1>(hk1), b2 = qbcast<2>(hk1), b3 = qbcast<3>(hk1);
                float z = bpv + b0 * wpv[0] + b1 * wpv[1] + b2 * wpv[2] + b3 * wpv[3];
                if (k == 0) prog[b * 128 + s] = fsigmoid(z);

                // ---- prefetch next step's xd from ring ----
                float nxt[8];
                if (s < 127) {
                    while (!__hip_atomic_load(&ready[s + 1], __ATOMIC_ACQUIRE, WG))
                        __builtin_amdgcn_s_sleep(1);
                    int sb = ((s + 1) & 15) * 512;
#pragma unroll
                    for (int i = 0; i < 8; ++i) nxt[i] = ring[sb + i * 64 + tid];
                    asm volatile("s_waitcnt lgkmcnt(0)" ::: "memory");
                    if (tid == 0)
                        __hip_atomic_store(&consumed, s + 2, __ATOMIC_RELEASE, WG);
                }

                // ---- cell 2 (from h1, c1; its c is discarded) ----
                float e0 = cur[4] + b0 * whh_r[0][0] + b1 * whh_r[0][1] + b2 * whh_r[0][2] + b3 * whh_r[0][3];
                float e1 = cur[5] + b0 * whh_r[1][0] + b1 * whh_r[1][1] + b2 * whh_r[1][2] + b3 * whh_r[1][3];
                float e2 = cur[6] + b0 * whh_r[2][0] + b1 * whh_r[2][1] + b2 * whh_r[2][2] + b3 * whh_r[2][3];
                float e3 = cur[7] + b0 * whh_r[3][0] + b1 * whh_r[3][1] + b2 * whh_r[3][2] + b3 * whh_r[3][3];
                float c2v = fsigmoid(e1) * c1 + fsigmoid(e0) * ftanh(e2);
                float hk2 = fsigmoid(e3) * ftanh(c2v);
                float d0 = qbcast<0>(hk2), d1 = qbcast<1>(hk2), d2 = qbcast<2>(hk2), d3 = qbcast<3>(hk2);
                float z2 = bpv + d0 * wpv[0] + d1 * wpv[1] + d2 * wpv[2] + d3 * wpv[3];
                if (k == 0) fprog[b * 128 + s] = fsigmoid(z2);

                h0 = b0; h1r = b1; h2r = b2; h3r = b3; ck = c1;
                if (s < 127) {
#pragma unroll
                    for (int i = 0; i < 8; ++i) cur[i] = nxt[i];
                }
            }
        } else {
            // ---- copy/xd waves: wave w handles steps s = (w-1) + 6j ----
            int l = tid & 63;
            int b = l >> 2, k = l & 3;
            float wih_r[4][8], bsum[4];
#pragma unroll
            for (int g = 0; g < 4; g++) {
                int row = g * 4 + k;
#pragma unroll
                for (int m = 0; m < 8; m++) wih_r[g][m] = Wih[row * 8 + m];
                bsum[g] = bih[row] + bhh[row];
            }
            const float* eb = emb + b * 1024;   // b*128*8
            const float* fb = femb + b * 1024;
            for (int s = w - 1; s < 128; s += 6) {
                while (__hip_atomic_load(&consumed, __ATOMIC_RELAXED, WG) < s - 15)
                    __builtin_amdgcn_s_sleep(2);
                while (__hip_atomic_load(&cnt[s], __ATOMIC_ACQUIRE, AGENT) < 16)
                    __builtin_amdgcn_s_sleep(4);
                const float4* pe = (const float4*)(eb + s * 8);
                float4 xa = pe[0], xb = pe[1];
                const float4* pf = (const float4*)(fb + s * 8);
                float4 xc = pf[0], xdv = pf[1];
                int sb = (s & 15) * 512 + l;
#pragma unroll
                for (int g = 0; g < 4; ++g) {
                    ring[sb + g * 64]       = bsum[g] + dot8(xa, xb, wih_r[g]);
                    ring[sb + (4 + g) * 64] = bsum[g] + dot8(xc, xdv, wih_r[g]);
                }
                asm volatile("s_waitcnt lgkmcnt(0)" ::: "memory");
                if (l == 0)
                    __hip_atomic_store(&ready[s], 1, __ATOMIC_RELEASE, WG);
            }
        }
        return;
    }

    // ---------------- producer: image n = blockIdx.x - 1 (round-9 stream) ----------------
    int n = blockIdx.x - 1;
    const fvec4* __restrict__ base =
        reinterpret_cast<const fvec4*>(frames) + (size_t)n * 37632;  // 3*224*56
    int cc = tid % 56;
    bool left = cc < 28;

    __shared__ float sred[7][4];
    __shared__ float sq[3][4];
    __shared__ float sp[15], sfc[15];

    for (int c = 0; c < 3; ++c) {
        const fvec4* __restrict__ p = base + c * 12544 + tid;
        float aT = NEGINF, aB = NEGINF;
#pragma unroll 7
        for (int r = 0; r < 14; ++r) {       // rows 0..111
            fvec4 f = __builtin_nontemporal_load(&p[r * 448]);
            aT = fmaxf(aT, fmaxf(fmaxf(f.x, f.y), fmaxf(f.z, f.w)));
        }
#pragma unroll 7
        for (int r = 14; r < 28; ++r) {      // rows 112..223
            fvec4 f = __builtin_nontemporal_load(&p[r * 448]);
            aB = fmaxf(aB, fmaxf(fmaxf(f.x, f.y), fmaxf(f.z, f.w)));
        }
        float tl = left ? aT : NEGINF;
        float tr = left ? NEGINF : aT;
        float bl = left ? aB : NEGINF;
        float br = left ? NEGINF : aB;
#pragma unroll
        for (int m = 32; m >= 1; m >>= 1) {
            tl = fmaxf(tl, __shfl_xor(tl, m, 64));
            tr = fmaxf(tr, __shfl_xor(tr, m, 64));
            bl = fmaxf(bl, __shfl_xor(bl, m, 64));
            br = fmaxf(br, __shfl_xor(br, m, 64));
        }
        int w = tid >> 6;
        if ((tid & 63) == 0) { sred[w][0] = tl; sred[w][1] = tr; sred[w][2] = bl; sred[w][3] = br; }
        __syncthreads();
        if (tid < 4) {
            float v = sred[0][tid];
#pragma unroll
            for (int ww = 1; ww < 7; ++ww) v = fmaxf(v, sred[ww][tid]);
            sq[c][tid] = v;
        }
        __syncthreads();  // sred reused next channel
    }

    // ---- prep tail (amortized inside the stream) ----
    if (tid < 12) {
        sp[tid] = ((const float*)sq)[tid];  // sp[c*4+q] = sq[c][q]
    } else if (tid >= 16 && tid < 19) {
        int c = tid - 16;
        sp[12 + c] = fmaxf(fmaxf(sq[c][0], sq[c][1]), fmaxf(sq[c][2], sq[c][3]));
    }
    __syncthreads();
    if (tid < 15) {
        float a = bf[tid];
#pragma unroll
        for (int kk = 0; kk < 15; ++kk) a += sp[kk] * Wf[tid * 15 + kk];
        sfc[tid] = a;
        out_pooled[n * 15 + tid] = sp[tid];
        out_fc[n * 15 + tid] = a;
    }
    __syncthreads();
    if (tid < 8) {
        float a = be[tid], a2 = be[tid];
#pragma unroll
        for (int kk = 0; kk < 15; ++kk) {
            a  += sp[kk]  * We[tid * 15 + kk];
            a2 += sfc[kk] * We[tid * 15 + kk];
        }
        __hip_atomic_store(&emb[n * 8 + tid],  a,  __ATOMIC_RELAXED, AGENT);
        __hip_atomic_store(&femb[n * 8 + tid], a2, __ATOMIC_RELAXED, AGENT);
    }
    __syncthreads();
    if (tid == 0)
        __hip_atomic_fetch_add(&cnt[n & 127], 1, __ATOMIC_RELEASE, AGENT);
}

extern "C" void kernel_launch(void* const* d_in, const int* in_sizes, int n_in,
                              void* d_out, int out_size, void* d_ws, size_t ws_size,
                              hipStream_t stream) {
    const float* frames = (const float*)d_in[0];
    const float* Wf     = (const float*)d_in[1];
    const float* bf     = (const float*)d_in[2];
    const float* We     = (const float*)d_in[3];
    const float* be     = (const float*)d_in[4];
    const float* Wih    = (const float*)d_in[5];
    const float* Whh    = (const float*)d_in[6];
    const float* bih    = (const float*)d_in[7];
    const float* bhh    = (const float*)d_in[8];
    const float* Wp     = (const float*)d_in[9];
    const float* bp     = (const float*)d_in[10];

    float* out = (float*)d_out;
    float* out_prog   = out;                  // (16,128)
    float* out_fprog  = out + 2048;           // (16,128)
    float* out_pooled = out + 4096;           // (16,128,15)
    float* out_fc     = out + 4096 + 30720;   // (16,128,15)

    char* ws = (char*)d_ws;
    int*   cnt  = (int*)ws;                       // 128 ints
    float* emb  = (float*)(ws + 512);             // 2048*8 floats
    float* femb = (float*)(ws + 512 + 65536);     // 2048*8 floats

    hipMemsetAsync(cnt, 0, 128 * sizeof(int), stream);
    fused_kernel<<<2049, 448, 32768, stream>>>(frames, Wf, bf, We, be, Wih, Whh,
                                               bih, bhh, Wp, bp, out_pooled,
                                               out_fc, out_prog, out_fprog,
                                               cnt, emb, femb);
}

// Round 12
// 273.745 us; speedup vs baseline: 1.3186x; 1.3186x over previous
//
#include <hip/hip_runtime.h>
#include <math.h>

#define NEGINF (-INFINITY)

typedef float fvec4 __attribute__((ext_vector_type(4)));

template <int M>
__device__ __forceinline__ float qbcast(float v) {
    // DPP quad_perm broadcast of lane M within each 4-lane quad (VALU, no LDS)
    return __int_as_float(
        __builtin_amdgcn_update_dpp(0, __float_as_int(v), M * 0x55, 0xF, 0xF, true));
}
__device__ __forceinline__ float fsigmoid(float z) { return 1.f / (1.f + __expf(-z)); }
__device__ __forceinline__ float ftanh(float z) {
    z = fminf(fmaxf(z, -20.f), 20.f);
    float e = __expf(2.f * z);
    return (e - 1.f) / (e + 1.f);
}

// ---------------- Kernel 1: per-image SPP + prep (2048 blocks x 448) ----------------
// Round-9 stream + ONE change: XCD-bijective block->image swizzle so each XCD
// streams a contiguous 154 MB region in sequential order (DRAM page locality).
__global__ __launch_bounds__(448, 7) void spp_prep_kernel(
    const float* __restrict__ frames, const float* __restrict__ Wf,
    const float* __restrict__ bf, const float* __restrict__ We,
    const float* __restrict__ be, float* __restrict__ out_pooled,
    float* __restrict__ out_fc, float* __restrict__ emb,
    float* __restrict__ femb) {
    int bid = blockIdx.x;
    int n = (bid & 7) * 256 + (bid >> 3);  // XCD-bijective swizzle (2048 = 8*256)
    int tid = threadIdx.x;
    const fvec4* __restrict__ base =
        reinterpret_cast<const fvec4*>(frames) + (size_t)n * 37632;  // 3*224*56
    int cc = tid % 56;
    bool left = cc < 28;

    __shared__ float sred[7][4];
    __shared__ float sq[3][4];
    __shared__ float sp[15], sfc[15];

    for (int c = 0; c < 3; ++c) {
        const fvec4* __restrict__ p = base + c * 12544 + tid;
        float aT = NEGINF, aB = NEGINF;
#pragma unroll 7
        for (int r = 0; r < 14; ++r) {       // rows 0..111
            fvec4 f = __builtin_nontemporal_load(&p[r * 448]);
            aT = fmaxf(aT, fmaxf(fmaxf(f.x, f.y), fmaxf(f.z, f.w)));
        }
#pragma unroll 7
        for (int r = 14; r < 28; ++r) {      // rows 112..223
            fvec4 f = __builtin_nontemporal_load(&p[r * 448]);
            aB = fmaxf(aB, fmaxf(fmaxf(f.x, f.y), fmaxf(f.z, f.w)));
        }
        float tl = left ? aT : NEGINF;
        float tr = left ? NEGINF : aT;
        float bl = left ? aB : NEGINF;
        float br = left ? NEGINF : aB;
#pragma unroll
        for (int m = 32; m >= 1; m >>= 1) {
            tl = fmaxf(tl, __shfl_xor(tl, m, 64));
            tr = fmaxf(tr, __shfl_xor(tr, m, 64));
            bl = fmaxf(bl, __shfl_xor(bl, m, 64));
            br = fmaxf(br, __shfl_xor(br, m, 64));
        }
        int w = tid >> 6;
        if ((tid & 63) == 0) { sred[w][0] = tl; sred[w][1] = tr; sred[w][2] = bl; sred[w][3] = br; }
        __syncthreads();
        if (tid < 4) {
            float v = sred[0][tid];
#pragma unroll
            for (int ww = 1; ww < 7; ++ww) v = fmaxf(v, sred[ww][tid]);
            sq[c][tid] = v;
        }
        __syncthreads();  // sred reused next channel
    }

    // ---- prep tail (amortized inside the stream) ----
    if (tid < 12) {
        sp[tid] = ((const float*)sq)[tid];  // sp[c*4+q] = sq[c][q]
    } else if (tid >= 16 && tid < 19) {
        int c = tid - 16;
        sp[12 + c] = fmaxf(fmaxf(sq[c][0], sq[c][1]), fmaxf(sq[c][2], sq[c][3]));
    }
    __syncthreads();
    if (tid < 15) {
        float a = bf[tid];
#pragma unroll
        for (int kk = 0; kk < 15; ++kk) a += sp[kk] * Wf[tid * 15 + kk];
        sfc[tid] = a;
        out_pooled[n * 15 + tid] = sp[tid];
        out_fc[n * 15 + tid] = a;
    }
    __syncthreads();
    if (tid < 8) {
        float a = be[tid], a2 = be[tid];
#pragma unroll
        for (int kk = 0; kk < 15; ++kk) {
            a  += sp[kk]  * We[tid * 15 + kk];
            a2 += sfc[kk] * We[tid * 15 + kk];
        }
        emb[n * 8 + tid]  = a;
        femb[n * 8 + tid] = a2;
    }
}

// ---------------- Kernel 2: LDS-staged double-cell LSTM (unchanged, round 9) ----------------
#define BSTRIDE 1036  // floats per batch in LDS: 128*8 + 12 pad

__device__ __forceinline__ float dot8(const float4& a, const float4& b,
                                      const float* __restrict__ w) {
    return a.x * w[0] + a.y * w[1] + a.z * w[2] + a.w * w[3] +
           b.x * w[4] + b.y * w[5] + b.z * w[6] + b.w * w[7];
}

__global__ __launch_bounds__(512, 1) void lstm_kernel(
    const float* __restrict__ emb, const float* __restrict__ femb,
    const float* __restrict__ Wih, const float* __restrict__ Whh,
    const float* __restrict__ bih, const float* __restrict__ bhh,
    const float* __restrict__ Wp, const float* __restrict__ bp,
    float* __restrict__ prog, float* __restrict__ fprog) {
    extern __shared__ float lds[];
    float* lemb  = lds;                  // [16][BSTRIDE]
    float* lfemb = lds + 16 * BSTRIDE;   // [16][BSTRIDE]
    int tid = threadIdx.x;

    // ---- Phase 0: bulk copy global -> LDS (4096 float4 per buffer) ----
    const fvec4* ge = reinterpret_cast<const fvec4*>(emb);
    const fvec4* gf = reinterpret_cast<const fvec4*>(femb);
#pragma unroll
    for (int it = 0; it < 8; ++it) {
        int g = it * 512 + tid;          // 0..4095
        int n = g >> 1;                  // image index
        int dst = (n >> 7) * BSTRIDE + (n & 127) * 8 + (g & 1) * 4;
        fvec4 ve = ge[g];
        fvec4 vf = gf[g];
        *reinterpret_cast<fvec4*>(&lemb[dst])  = ve;
        *reinterpret_cast<fvec4*>(&lfemb[dst]) = vf;
    }
    __syncthreads();

    // ---- Phase 1: double-cell LSTM, one wave (16 batches x 4 hidden lanes) ----
    if (tid >= 64) return;
    int b = tid >> 2, k = tid & 3;
    float wih[4][8], whh[4][4], bsum[4];
#pragma unroll
    for (int g = 0; g < 4; g++) {
        int row = g * 4 + k;
#pragma unroll
        for (int m = 0; m < 8; m++) wih[g][m] = Wih[row * 8 + m];
#pragma unroll
        for (int m = 0; m < 4; m++) whh[g][m] = Whh[row * 4 + m];
        bsum[g] = bih[row] + bhh[row];
    }
    float wpv[4];
#pragma unroll
    for (int m = 0; m < 4; m++) wpv[m] = Wp[m];
    float bpv = bp[0];

    const float* xe = lemb  + b * BSTRIDE;
    const float* xf = lfemb + b * BSTRIDE;

    // x-dots for step 0 (carry-independent part of the gates)
    float xd1[4], xd2[4];
    {
        float4 a0 = *(const float4*)(xe);
        float4 a1 = *(const float4*)(xe + 4);
        float4 f0 = *(const float4*)(xf);
        float4 f1 = *(const float4*)(xf + 4);
#pragma unroll
        for (int g = 0; g < 4; g++) {
            xd1[g] = bsum[g] + dot8(a0, a1, wih[g]);
            xd2[g] = bsum[g] + dot8(f0, f1, wih[g]);
        }
    }

    float h0 = 0.f, h1r = 0.f, h2r = 0.f, h3r = 0.f;
    float ck = 0.f;

    for (int s2 = 0; s2 < 128; ++s2) {
        // prefetch next step's x (s2=127 reads the pad region: harmless, unused)
        const float* nxe = xe + (s2 + 1) * 8;
        const float* nxf = xf + (s2 + 1) * 8;
        float4 na0 = *(const float4*)(nxe);
        float4 na1 = *(const float4*)(nxe + 4);
        float4 nf0 = *(const float4*)(nxf);
        float4 nf1 = *(const float4*)(nxf + 4);

        // ---- cell 1 ----
        float g0 = xd1[0] + h0 * whh[0][0] + h1r * whh[0][1] + h2r * whh[0][2] + h3r * whh[0][3];
        float g1 = xd1[1] + h0 * whh[1][0] + h1r * whh[1][1] + h2r * whh[1][2] + h3r * whh[1][3];
        float g2 = xd1[2] + h0 * whh[2][0] + h1r * whh[2][1] + h2r * whh[2][2] + h3r * whh[2][3];
        float g3 = xd1[3] + h0 * whh[3][0] + h1r * whh[3][1] + h2r * whh[3][2] + h3r * whh[3][3];
        float c1  = fsigmoid(g1) * ck + fsigmoid(g0) * ftanh(g2);
        float hk1 = fsigmoid(g3) * ftanh(c1);
        float b0 = qbcast<0>(hk1), b1 = qbcast<1>(hk1), b2 = qbcast<2>(hk1), b3 = qbcast<3>(hk1);
        float z = bpv + b0 * wpv[0] + b1 * wpv[1] + b2 * wpv[2] + b3 * wpv[3];
        if (k == 0) prog[b * 128 + s2] = fsigmoid(z);

        // ---- cell 2 (from h1, c1; its c is discarded) ----
        float e0 = xd2[0] + b0 * whh[0][0] + b1 * whh[0][1] + b2 * whh[0][2] + b3 * whh[0][3];
        float e1 = xd2[1] + b0 * whh[1][0] + b1 * whh[1][1] + b2 * whh[1][2] + b3 * whh[1][3];
        float e2 = xd2[2] + b0 * whh[2][0] + b1 * whh[2][1] + b2 * whh[2][2] + b3 * whh[2][3];
        float e3 = xd2[3] + b0 * whh[3][0] + b1 * whh[3][1] + b2 * whh[3][2] + b3 * whh[3][3];
        float c2v = fsigmoid(e1) * c1 + fsigmoid(e0) * ftanh(e2);
        float hk2 = fsigmoid(e3) * ftanh(c2v);
        float d0 = qbcast<0>(hk2), d1 = qbcast<1>(hk2), d2 = qbcast<2>(hk2), d3 = qbcast<3>(hk2);
        float z2 = bpv + d0 * wpv[0] + d1 * wpv[1] + d2 * wpv[2] + d3 * wpv[3];
        if (k == 0) fprog[b * 128 + s2] = fsigmoid(z2);

        // carry = (h1, c1)
        h0 = b0; h1r = b1; h2r = b2; h3r = b3; ck = c1;

        // next step's carry-independent x-dots (off the critical path)
#pragma unroll
        for (int g = 0; g < 4; g++) {
            xd1[g] = bsum[g] + dot8(na0, na1, wih[g]);
            xd2[g] = bsum[g] + dot8(nf0, nf1, wih[g]);
        }
    }
}

extern "C" void kernel_launch(void* const* d_in, const int* in_sizes, int n_in,
                              void* d_out, int out_size, void* d_ws, size_t ws_size,
                              hipStream_t stream) {
    const float* frames = (const float*)d_in[0];
    const float* Wf     = (const float*)d_in[1];
    const float* bf     = (const float*)d_in[2];
    const float* We     = (const float*)d_in[3];
    const float* be     = (const float*)d_in[4];
    const float* Wih    = (const float*)d_in[5];
    const float* Whh    = (const float*)d_in[6];
    const float* bih    = (const float*)d_in[7];
    const float* bhh    = (const float*)d_in[8];
    const float* Wp     = (const float*)d_in[9];
    const float* bp     = (const float*)d_in[10];

    float* out = (float*)d_out;
    float* out_prog   = out;                  // (16,128)
    float* out_fprog  = out + 2048;           // (16,128)
    float* out_pooled = out + 4096;           // (16,128,15)
    float* out_fc     = out + 4096 + 30720;   // (16,128,15)

    float* ws_f = (float*)d_ws;
    float* emb  = ws_f;                       // 2048*8 floats
    float* femb = ws_f + 16384;               // 2048*8 floats

    spp_prep_kernel<<<2048, 448, 0, stream>>>(frames, Wf, bf, We, be, out_pooled,
                                              out_fc, emb, femb);
    size_t lds_bytes = (size_t)2 * 16 * BSTRIDE * sizeof(float);  // 132,608 B
    lstm_kernel<<<1, 512, lds_bytes, stream>>>(emb, femb, Wih, Whh, bih, bhh,
                                               Wp, bp, out_prog, out_fprog);
}